// Round 5
// baseline (137.730 us; speedup 1.0000x reference)
//
#include <hip/hip_runtime.h>

// B=8, C=64, H=W=64, CI=32, N=4096 pixels, M=1024 pooled.
// y[b,n,:] = (a_n*S1[k_n,:] + S2[k_n,:])/1024 ; only W_w . y is needed, so
// track U = Ww.psi (64-dim) and its sorted-order prefixes T1/T2 directly.
// BN stats from per-k scalars (cnt, sum a, sum a^2) x T rows - no Gram.
//
// r10: (a) hipMemsetAsync node removed -- accounting across rounds shows it
// cost ~30us/iter (SDMA cross-engine sync in the graph); barrier slots are
// zeroed by a tiny kernel node, hist is zeroed inside kMega P1 (disjoint
// slices, consumed first in P2 -- safe). (b) barrier arrival RMWs replaced
// by per-block sc1 STORES (fire-and-forget, no same-line serialization);
// detection = one wave polls all 256 slots (4 coalesced lines). Release
// ordering = vmcnt drain at __syncthreads before the arrival store (same
// model r9 validated). All cross-block data stays on sc1 (L2-bypass,
// coherence point), so no wbl2/inv anywhere.
#define OFF_A    0         // a[b][n]               : 32768 floats
#define OFF_BB   32768     // bb[b][m]              : 8192
#define OFF_SBB  40960     // sorted-desc bb[b][k]  : 8192
#define OFF_PERM 49152     // perm[b][k] (int)      : 8192
#define OFF_U    57344     // U[b][m][o]            : 8*1024*64 = 524288
#define OFF_T1   581632    // T1[b][k<=1024][o]     : 8*1025*64 = 524800
#define OFF_T2   1106432   // T2[b][k][o]           : 524800
#define OFF_KK   1631232   // k[b][n] (int)         : 32768
#define OFF_MP1  1664000   // moment1 partials [b3][o] : 512
#define OFF_MP2  1664512   // moment2 partials [b3][o] : 512
#define OFF_HC   1665024   // hist cnt[b][1025]     : 8200
#define OFF_HS   1673224   // hist sum_a[b][1025]   : 8200
#define OFF_HS2  1681424   // hist sum_a2[b][1025]  : 8200
#define OFF_BAR  1689624   // arrival slots: 256 u32 (zeroed by kZero)

#define NBLK 256

// Coherent (sc1, L2-bypass) scalar access helpers for cross-block data.
__device__ __forceinline__ void stg(float* p, float v) {
    __hip_atomic_store(p, v, __ATOMIC_RELAXED, __HIP_MEMORY_SCOPE_AGENT);
}
__device__ __forceinline__ float ldg1(const float* p) {
    return __hip_atomic_load(p, __ATOMIC_RELAXED, __HIP_MEMORY_SCOPE_AGENT);
}
__device__ __forceinline__ void stgi(int* p, int v) {
    __hip_atomic_store(p, v, __ATOMIC_RELAXED, __HIP_MEMORY_SCOPE_AGENT);
}
__device__ __forceinline__ int ldgi(const int* p) {
    return __hip_atomic_load(p, __ATOMIC_RELAXED, __HIP_MEMORY_SCOPE_AGENT);
}

// Store/poll grid barrier: no RMWs at all. __syncthreads drains vmcnt
// (prior sc1 data stores are at the coherence point), tid0 stores the
// generation to this block's own slot, wave 0 polls all 256 slots (4
// coalesced 256B lines) until everyone's generation >= gen.
__device__ __forceinline__ void gbar(float* ws, unsigned gen)
{
    __syncthreads();
    unsigned* slots = (unsigned*)(ws + OFF_BAR);
    if (threadIdx.x == 0)
        __hip_atomic_store(&slots[blockIdx.x], gen, __ATOMIC_RELAXED,
                           __HIP_MEMORY_SCOPE_AGENT);
    if (threadIdx.x < 64) {
        for (;;) {
            unsigned mn = 0xffffffffu;
            #pragma unroll
            for (int r = 0; r < 4; ++r) {
                unsigned v = __hip_atomic_load(&slots[(r<<6) + threadIdx.x],
                                               __ATOMIC_RELAXED,
                                               __HIP_MEMORY_SCOPE_AGENT);
                mn = v < mn ? v : mn;
            }
            if (__all(mn >= gen)) break;
            __builtin_amdgcn_s_sleep(2);
        }
    }
    __syncthreads();
}

// Tiny init kernel: zero the 256 arrival slots (sc1 so kMega's sc1 polls
// see them regardless of cache state).
__global__ void kZero(float* ws)
{
    unsigned* slots = (unsigned*)(ws + OFF_BAR);
    __hip_atomic_store(&slots[threadIdx.x], 0u, __ATOMIC_RELAXED,
                       __HIP_MEMORY_SCOPE_AGENT);
}

// LDS carve (floats), phases reuse one 8640-float block (34.6 KB):
// P1: sm[0..4160) sth[4160..4228) spsi[4228..5284) sWw[5284..7396)
// P2: sb[0..1024)
// P3: ssort[0..1024) sperm[1024..2048) shc[2048..3076) shs[3076..4104)
//     shs2[4104..5132) swp1[5132..5260) swp2[5260..5388)
// P4: tile[0..8256)=64x129 sa[8256..8384) sk[8384..8512) sA[8512..8576)
//     sD[8576..8640)
__global__ __launch_bounds__(1024) void kMega(
    const float* __restrict__ x, const float* __restrict__ theta_w,
    const float* __restrict__ theta_b, const float* __restrict__ phi_w,
    const float* __restrict__ phi_b, const float* __restrict__ psi_w,
    const float* __restrict__ psi_b, const float* __restrict__ cp_w,
    const float* __restrict__ Ww, const float* __restrict__ Wb,
    const float* __restrict__ gamma, const float* __restrict__ beta,
    float* __restrict__ ws, float* __restrict__ out)
{
    __shared__ float sh[8640];
    const int tid = threadIdx.x;
    const int bid = blockIdx.x;
    const int b   = bid >> 5;     // 32 blocks per batch image
    const int sub = bid & 31;

    // ---------- Phase 1: phi/psi conv+pool -> bb, U ; theta -> a ----------
    {
        // zero this block's disjoint hist slice (consumed in P2, after
        // gbar(1) -- our stores are drained by gbar's __syncthreads).
        if (tid < 97) {
            int e = bid*97 + tid;
            if (e < 24600) stg(&ws[OFF_HC + e], 0.0f);
        }
        float* sm   = sh;          // 32 i-rows x 130: interleaved {phi,psi}
        float* sth  = sh + 4160;   // tw_eff[64] + tb_eff
        float* spsi = sh + 4228;   // 32 m-rows x 32 i (pad 33)
        float* sWw  = sh + 5284;   // 64 o-rows x 32 i (pad 33)
        for (int e = tid; e < 2048; e += 1024) {
            int i = e >> 6, c = e & 63;
            sm[i*130 + 2*c]     = phi_w[e];
            sm[i*130 + 2*c + 1] = psi_w[e];
        }
        for (int e = tid; e < 2048; e += 1024)
            sWw[(e >> 5)*33 + (e & 31)] = Ww[(e >> 5)*33 + (e & 31)];
        if (tid < 64) {
            float s = 0;
            for (int i = 0; i < 32; ++i) s += cp_w[i]*theta_w[i*64 + tid];
            sth[tid] = s;
        } else if (tid == 64) {
            float s = 0;
            for (int i = 0; i < 32; ++i) s += cp_w[i]*theta_b[i];
            sth[64] = s;
        }
        __syncthreads();
        int i = tid & 31;
        int mIdx = tid >> 5;                 // 0..31
        int m = (sub << 5) + mIdx;
        int ph = m >> 5, pw = m & 31;
        const float* xb = x + b*262144 + ph*128 + pw*2;
        const float2* wrow = (const float2*)(sm + i*130);
        float tb = sth[64];
        float p0=0,p1=0,p2=0,p3=0,s0=0,s1=0,s2=0,s3=0;
        float a0=tb,a1=tb,a2=tb,a3=tb;       // theta: bias-first like before
        #pragma unroll 8
        for (int c = 0; c < 64; ++c) {
            float2 xa = *(const float2*)(xb + c*4096);
            float2 xc = *(const float2*)(xb + c*4096 + 64);
            float2 w  = wrow[c];             // {phi_w, psi_w}
            float st  = sth[c];              // broadcast read
            p0 += xa.x*w.x; p1 += xa.y*w.x; p2 += xc.x*w.x; p3 += xc.y*w.x;
            s0 += xa.x*w.y; s1 += xa.y*w.y; s2 += xc.x*w.y; s3 += xc.y*w.y;
            a0 += xa.x*st;  a1 += xa.y*st;  a2 += xc.x*st;  a3 += xc.y*st;
        }
        float pv = fmaxf(fmaxf(p0,p1), fmaxf(p2,p3)) + phi_b[i];
        float sv = fmaxf(fmaxf(s0,s1), fmaxf(s2,s3)) + psi_b[i];
        spsi[mIdx*33 + i] = sv;
        float v = pv * cp_w[32 + i];
        v += __shfl_xor(v, 16, 32);
        v += __shfl_xor(v,  8, 32);
        v += __shfl_xor(v,  4, 32);
        v += __shfl_xor(v,  2, 32);
        v += __shfl_xor(v,  1, 32);
        if (i == 0) {
            stg(&ws[OFF_BB + (b<<10) + m], v);
            int nb = (b<<12) + ph*128 + pw*2;   // pixel (2ph,2pw)
            stg(&ws[OFF_A + nb],      a0);
            stg(&ws[OFF_A + nb + 1],  a1);
            stg(&ws[OFF_A + nb + 64], a2);
            stg(&ws[OFF_A + nb + 65], a3);
        }
        __syncthreads();
        #pragma unroll
        for (int rep = 0; rep < 2; ++rep) {
            int idx = tid + (rep << 10);     // 2048 outputs = 32 m x 64 o
            int ml = idx >> 6, o = idx & 63;
            const float* pr = &spsi[ml*33];  // wave-uniform ml: broadcast
            const float* wr = &sWw[o*33];    // (o+i)%32: 2-way max (free)
            float u = 0;
            #pragma unroll
            for (int i2 = 0; i2 < 32; ++i2) u += pr[i2]*wr[i2];
            stg(&ws[OFF_U + (((b<<10) + (sub<<5) + ml) << 6) + o], u);
        }
    }
    gbar(ws, 1u);

    // ---------- Phase 2: rank bb, k_n per pixel, per-b histogram ----------
    {
        float* sb = sh;
        sb[tid] = ldg1(&ws[OFF_BB + (b<<10) + tid]);
        __syncthreads();
        {   // rank 32 m's of this chunk (32 lanes per m, integer-exact)
            int ml = tid >> 5, jl = tid & 31;
            int m = (sub << 5) + ml;
            float vv = sb[m];
            int cnt = 0;
            for (int s = 0; s < 32; ++s) {
                int j = jl + (s << 5);
                float u = sb[j];
                cnt += (u > vv || (u == vv && j < m)) ? 1 : 0;
            }
            cnt += __shfl_xor(cnt,  1, 32);
            cnt += __shfl_xor(cnt,  2, 32);
            cnt += __shfl_xor(cnt,  4, 32);
            cnt += __shfl_xor(cnt,  8, 32);
            cnt += __shfl_xor(cnt, 16, 32);
            if (jl == 0) {
                stg(&ws[OFF_SBB + (b<<10) + cnt], vv);
                stgi(&((int*)ws)[OFF_PERM + (b<<10) + cnt], m);
            }
        }
        {   // k_n for 128 pixels (8 lanes per pixel) + hist atomics
            int l = tid >> 3, jl = tid & 7;
            int n = (sub << 7) + l;
            float av = ldg1(&ws[OFF_A + (b<<12) + n]);
            float tt = -av;
            const float2* sb2 = (const float2*)sb;
            int cnt = 0;
            for (int s = 0; s < 64; ++s) {
                float2 u = sb2[jl + (s << 3)];  // 8 distinct addrs: free
                cnt += (u.x > tt) ? 1 : 0;
                cnt += (u.y > tt) ? 1 : 0;
            }
            cnt += __shfl_xor(cnt, 1, 8);
            cnt += __shfl_xor(cnt, 2, 8);
            cnt += __shfl_xor(cnt, 4, 8);
            if (jl == 0) {
                stgi(&((int*)ws)[OFF_KK + (b<<12) + n], cnt);
                atomicAdd(&ws[OFF_HC + b*1025 + cnt], 1.0f);
                atomicAdd(&ws[OFF_HS + b*1025 + cnt], av);
                atomicAdd(&ws[OFF_HS2 + b*1025 + cnt], av*av);
            }
        }
    }
    gbar(ws, 2u);

    // ---------- Phase 3: sorted prefixes T1/T2 + BN moment partials ------
    // Exact kPS structure (bitwise-identical T1/T2); blocks 0..63 active.
    if (bid < 64) {
        int b3 = bid >> 3, og = bid & 7;
        int obase = og << 3;
        float* ssort = sh;
        int*   sperm = (int*)(sh + 1024);
        float* shc   = sh + 2048;
        float* shs   = sh + 3076;
        float* shs2  = sh + 4104;
        float* swp1  = sh + 5132;
        float* swp2  = sh + 5260;
        ssort[tid] = ldg1(&ws[OFF_SBB + (b3<<10) + tid]);
        sperm[tid] = ldgi(&((const int*)ws)[OFF_PERM + (b3<<10) + tid]);
        shc[tid]  = ldg1(&ws[OFF_HC  + b3*1025 + tid]);
        shs[tid]  = ldg1(&ws[OFF_HS  + b3*1025 + tid]);
        shs2[tid] = ldg1(&ws[OFF_HS2 + b3*1025 + tid]);
        if (tid == 0) {
            shc[1024]  = ldg1(&ws[OFF_HC  + b3*1025 + 1024]);
            shs[1024]  = ldg1(&ws[OFF_HS  + b3*1025 + 1024]);
            shs2[1024] = ldg1(&ws[OFF_HS2 + b3*1025 + 1024]);
        }
        __syncthreads();
        int ch = tid >> 3, o = tid & 7;
        int wv = tid >> 6, chl = (tid & 63) >> 3;   // ch = wv*8 + chl
        const float* Ub = ws + OFF_U + (b3<<16) + obase + o;
        float p[8], sp[8];
        float s1 = 0, s2 = 0;
        #pragma unroll
        for (int jl = 0; jl < 8; ++jl) {
            int jj = (ch<<3) + jl;
            float v = ldg1(&Ub[sperm[jj]<<6]);
            p[jl] = v;
            sp[jl] = ssort[jj]*v;
            s1 += v; s2 += sp[jl];
        }
        float own1 = s1, own2 = s2;
        #pragma unroll
        for (int d = 1; d < 8; d <<= 1) {
            float u1 = __shfl_up(s1, d<<3, 64);
            float u2 = __shfl_up(s2, d<<3, 64);
            if (chl >= d) { s1 += u1; s2 += u2; }
        }
        if (chl == 7) { swp1[(wv<<3)+o] = s1; swp2[(wv<<3)+o] = s2; }
        __syncthreads();
        float off1 = 0, off2 = 0;
        for (int w = 0; w < 16; ++w) {
            if (w < wv) { off1 += swp1[(w<<3)+o]; off2 += swp2[(w<<3)+o]; }
        }
        float run1 = off1 + s1 - own1;   // exclusive prefix before chunk ch
        float run2 = off2 + s2 - own2;
        float* T1 = ws + OFF_T1 + b3*65600 + obase + o;
        float* T2 = ws + OFF_T2 + b3*65600 + obase + o;
        if (ch == 0) { stg(&T1[0], 0.0f); stg(&T2[0], 0.0f); }  // k=0 row
        const float inv = 1.0f/1024.0f;
        float m1 = 0, m2 = 0;
        #pragma unroll
        for (int jl = 0; jl < 8; ++jl) {
            int k = (ch<<3) + jl + 1;
            run1 += p[jl]; run2 += sp[jl];
            float t1 = run1*inv, t2 = run2*inv;
            stg(&T1[k<<6], t1);
            stg(&T2[k<<6], t2);
            float c = shc[k], sa_ = shs[k], sa2 = shs2[k];
            m1 += sa_*t1 + c*t2;
            m2 += (sa2*t1 + 2.0f*sa_*t2)*t1 + c*t2*t2;
        }
        m1 += __shfl_xor(m1,  8, 64); m2 += __shfl_xor(m2,  8, 64);
        m1 += __shfl_xor(m1, 16, 64); m2 += __shfl_xor(m2, 16, 64);
        m1 += __shfl_xor(m1, 32, 64); m2 += __shfl_xor(m2, 32, 64);
        __syncthreads();   // swp reuse
        if (chl == 0) { swp1[(wv<<3)+o] = m1; swp2[(wv<<3)+o] = m2; }
        __syncthreads();
        if (tid < 8) {
            float a1 = 0, a2 = 0;
            for (int w = 0; w < 16; ++w) {
                a1 += swp1[(w<<3)+tid]; a2 += swp2[(w<<3)+tid];
            }
            // plain coherent writes; P4 reduces over b3
            stg(&ws[OFF_MP1 + (b3<<6) + obase + tid], a1);
            stg(&ws[OFF_MP2 + (b3<<6) + obase + tid], a2);
        }
    }
    gbar(ws, 3u);

    // ---------- Phase 4: output tile (128 pixels per block) --------------
    {
        float* tile = sh;               // 64 o x 129 (pad)
        float* sa = sh + 8256;          // a for 128 pixels
        int*   sk = (int*)(sh + 8384);  // k for 128 pixels
        float* sA = sh + 8512;
        float* sD = sh + 8576;
        int n0 = sub << 7;
        if (tid < 128) {
            sa[tid] = ldg1(&ws[OFF_A + (b<<12) + n0 + tid]);
            sk[tid] = ldgi(&((const int*)ws)[OFF_KK + (b<<12) + n0 + tid]);
        }
        if (tid < 64) {
            const float Ninv = 1.0f/32768.0f;
            float m1s = 0, m2s = 0;
            #pragma unroll
            for (int b3 = 0; b3 < 8; ++b3) {
                m1s += ldg1(&ws[OFF_MP1 + (b3<<6) + tid]);
                m2s += ldg1(&ws[OFF_MP2 + (b3<<6) + tid]);
            }
            float m1 = m1s * Ninv;
            float m2 = m2s * Ninv;
            float wb = Wb[tid];
            float mu  = m1 + wb;
            float E2  = m2 + 2.0f*wb*m1 + wb*wb;
            float var = E2 - mu*mu;
            float A = gamma[tid] * rsqrtf(var + 1e-5f);
            sA[tid] = A;
            sD[tid] = beta[tid] + A*(wb - mu);
        }
        __syncthreads();
        const float* T1 = ws + OFF_T1 + b*65600;
        const float* T2 = ws + OFF_T2 + b*65600;
        {
            int o = tid & 63, ng = tid >> 6;   // 16 groups x 8 n
            float Ao = sA[o], Do = sD[o];
            #pragma unroll
            for (int j = 0; j < 8; ++j) {
                int n = (ng << 3) + j;
                int k = sk[n];                 // wave-uniform -> T coalesced
                float a = sa[n];
                float t1 = ldg1(&T1[(k<<6) + o]);
                float t2 = ldg1(&T2[(k<<6) + o]);
                tile[o*129 + n] = Ao*(a*t1 + t2) + Do;
            }
        }
        __syncthreads();
        {
            int n = tid & 127, og = tid >> 7;  // 8 groups x 8 o
            #pragma unroll
            for (int j = 0; j < 8; ++j) {
                int o = (og << 3) + j;
                int idx = ((b<<6) + o)*4096 + n0 + n;
                out[idx] = tile[o*129 + n] + x[idx];
            }
        }
    }
}

extern "C" void kernel_launch(void* const* d_in, const int* in_sizes, int n_in,
                              void* d_out, int out_size, void* d_ws, size_t ws_size,
                              hipStream_t stream)
{
    const float* x       = (const float*)d_in[0];
    const float* theta_w = (const float*)d_in[1];
    const float* theta_b = (const float*)d_in[2];
    const float* phi_w   = (const float*)d_in[3];
    const float* phi_b   = (const float*)d_in[4];
    const float* psi_w   = (const float*)d_in[5];
    const float* psi_b   = (const float*)d_in[6];
    const float* cp_w    = (const float*)d_in[7];
    const float* Ww      = (const float*)d_in[8];
    const float* Wb      = (const float*)d_in[9];
    const float* gamma   = (const float*)d_in[10];
    const float* beta    = (const float*)d_in[11];
    float* ws  = (float*)d_ws;
    float* out = (float*)d_out;

    kZero<<<1, 256, 0, stream>>>(ws);
    kMega<<<256, 1024, 0, stream>>>(x, theta_w, theta_b, phi_w, phi_b,
                                    psi_w, psi_b, cp_w, Ww, Wb,
                                    gamma, beta, ws, out);
}

// Round 6
// 132.335 us; speedup vs baseline: 1.0408x; 1.0408x over previous
//
#include <hip/hip_runtime.h>

// B=8, C=64, H=W=64, CI=32, N=4096 pixels, M=1024 pooled.
// y[b,n,:] = (a_n*S1[k_n,:] + S2[k_n,:])/1024 ; only W_w . y is needed, so
// track U = Ww.psi (64-dim) and its sorted-order prefixes T1/T2 directly.
// BN stats from per-k scalars (cnt, sum a, sum a^2) x T rows - no Gram.
//
// r11: revert to r4's tree-RMW relaxed barrier (56us) -- r5's store/poll
// variant hammered the coherence point with 256 polling lanes/block and
// regressed to 76us. New: (1) gen1/gen2 are PER-BATCH 32-block barriers
// (P2/P3 only consume same-batch data): one RMW + local-counter poll, no
// root, no cross-batch skew. (2) P3 widened to all 256 blocks (2 o-cols
// per block) -> 4x parallelism on the latency-bound sc1 U-gather. (3) P4
// waits per-batch, gathers the tile raw, and polls the global root only
// before the BN affine -> straggler wait overlaps the gather. (4) kZero
// kernel removed: block0 zeroes counters in-kernel, publishes flag pair
// (A^B==0xFFFFFFFF, unreachable by uniform fill poison); hist zeroing is
// batch-local. All cross-block data via sc1 (L2-bypass); no wbl2/inv.
#define OFF_A    0         // a[b][n]               : 32768 floats
#define OFF_BB   32768     // bb[b][m]              : 8192
#define OFF_SBB  40960     // sorted-desc bb[b][k]  : 8192
#define OFF_PERM 49152     // perm[b][k] (int)      : 8192
#define OFF_U    57344     // U[b][m][o]            : 8*1024*64 = 524288
#define OFF_T1   581632    // T1[b][k<=1024][o]     : 8*1025*64 = 524800
#define OFF_T2   1106432   // T2[b][k][o]           : 524800
#define OFF_KK   1631232   // k[b][n] (int)         : 32768
#define OFF_MP1  1664000   // moment1 partials [b][o] : 512
#define OFF_MP2  1664512   // moment2 partials [b][o] : 512
#define OFF_HC   1665024   // hist cnt[b][1025]     : 8200
#define OFF_HS   1673224   // hist sum_a[b][1025]   : 8200
#define OFF_HS2  1681424   // hist sum_a2[b][1025]  : 8200
#define OFF_BAR  1689624   // u32: root@0, batch b@32*(b+1), flags@288,289

// Coherent (sc1, L2-bypass) scalar access helpers for cross-block data.
__device__ __forceinline__ void stg(float* p, float v) {
    __hip_atomic_store(p, v, __ATOMIC_RELAXED, __HIP_MEMORY_SCOPE_AGENT);
}
__device__ __forceinline__ float ldg1(const float* p) {
    return __hip_atomic_load(p, __ATOMIC_RELAXED, __HIP_MEMORY_SCOPE_AGENT);
}
__device__ __forceinline__ void stgi(int* p, int v) {
    __hip_atomic_store(p, v, __ATOMIC_RELAXED, __HIP_MEMORY_SCOPE_AGENT);
}
__device__ __forceinline__ int ldgi(const int* p) {
    return __hip_atomic_load(p, __ATOMIC_RELAXED, __HIP_MEMORY_SCOPE_AGENT);
}
__device__ __forceinline__ void stgu(unsigned* p, unsigned v) {
    __hip_atomic_store(p, v, __ATOMIC_RELAXED, __HIP_MEMORY_SCOPE_AGENT);
}
__device__ __forceinline__ unsigned ldgu(const unsigned* p) {
    return __hip_atomic_load(p, __ATOMIC_RELAXED, __HIP_MEMORY_SCOPE_AGENT);
}

// Per-batch barrier: 32 blocks of batch b arrive on ctr[b] (relaxed RMW,
// one cache line per batch, 8 lines in parallel device-wide), poll own
// counter. Release = vmcnt drain at the preceding __syncthreads (r9-model,
// HW-validated r4). goal = gen*32.
__device__ __forceinline__ void gbarBatch(float* ws, int b, unsigned goal)
{
    __syncthreads();
    if (threadIdx.x == 0) {
        unsigned* ctr = (unsigned*)(ws + OFF_BAR) + ((b + 1) << 5);
        __hip_atomic_fetch_add(ctr, 1u, __ATOMIC_RELAXED,
                               __HIP_MEMORY_SCOPE_AGENT);
        while (ldgu(ctr) < goal) __builtin_amdgcn_s_sleep(2);
    }
    __syncthreads();
}

// LDS carve (floats), phases reuse one 8640-float block (34.6 KB):
// P1: sm[0..4160) sth[4160..4228) spsi[4228..5284) sWw[5284..7396)
// P2: sb[0..1024)
// P3: ssort[0..1024) sperm[1024..2048) shc[2048..3076) shs[3076..4104)
//     shs2[4104..5132) swp1[5132..5164) swp2[5164..5196)
// P4: tile[0..8256)=64x129 sa[8256..8384) sk[8384..8512) sA[8512..8576)
//     sD[8576..8640)
__global__ __launch_bounds__(1024) void kMega(
    const float* __restrict__ x, const float* __restrict__ theta_w,
    const float* __restrict__ theta_b, const float* __restrict__ phi_w,
    const float* __restrict__ phi_b, const float* __restrict__ psi_w,
    const float* __restrict__ psi_b, const float* __restrict__ cp_w,
    const float* __restrict__ Ww, const float* __restrict__ Wb,
    const float* __restrict__ gamma, const float* __restrict__ beta,
    float* __restrict__ ws, float* __restrict__ out)
{
    __shared__ float sh[8640];
    const int tid = threadIdx.x;
    const int bid = blockIdx.x;
    const int b   = bid >> 5;     // 32 blocks per batch image
    const int sub = bid & 31;
    unsigned* bars = (unsigned*)(ws + OFF_BAR);

    // ---------- Phase 1: phi/psi conv+pool -> bb, U ; theta -> a ----------
    {
        if (bid == 0 && tid == 0) {     // zero root + 8 batch counters
            for (int i = 0; i < 9; ++i) stgu(&bars[i << 5], 0u);
        }
        // zero this block's slice of ITS OWN batch's hist (3075 floats
        // over 32 blocks); visible to batch peers at gen1 (vmcnt drained
        // at gbar's __syncthreads) -- consumed in P2.
        if (tid < 97) {
            int e = sub*97 + tid;
            if (e < 1025)      stg(&ws[OFF_HC  + b*1025 + e], 0.0f);
            else if (e < 2050) stg(&ws[OFF_HS  + b*1025 + e - 1025], 0.0f);
            else if (e < 3075) stg(&ws[OFF_HS2 + b*1025 + e - 2050], 0.0f);
        }
        float* sm   = sh;          // 32 i-rows x 130: interleaved {phi,psi}
        float* sth  = sh + 4160;   // tw_eff[64] + tb_eff
        float* spsi = sh + 4228;   // 32 m-rows x 32 i (pad 33)
        float* sWw  = sh + 5284;   // 64 o-rows x 32 i (pad 33)
        for (int e = tid; e < 2048; e += 1024) {
            int i = e >> 6, c = e & 63;
            sm[i*130 + 2*c]     = phi_w[e];
            sm[i*130 + 2*c + 1] = psi_w[e];
        }
        for (int e = tid; e < 2048; e += 1024)
            sWw[(e >> 5)*33 + (e & 31)] = Ww[(e >> 5)*33 + (e & 31)];
        if (tid < 64) {
            float s = 0;
            for (int i = 0; i < 32; ++i) s += cp_w[i]*theta_w[i*64 + tid];
            sth[tid] = s;
        } else if (tid == 64) {
            float s = 0;
            for (int i = 0; i < 32; ++i) s += cp_w[i]*theta_b[i];
            sth[64] = s;
        }
        __syncthreads();   // drains vmcnt -> block0's counter zeros visible
        if (bid == 0 && tid == 0) {    // publish ready flags (poison-proof)
            stgu(&bars[288], 0x5A5A5A5Au);
            stgu(&bars[289], 0xA5A5A5A5u);
        }
        int i = tid & 31;
        int mIdx = tid >> 5;                 // 0..31
        int m = (sub << 5) + mIdx;
        int ph = m >> 5, pw = m & 31;
        const float* xb = x + b*262144 + ph*128 + pw*2;
        const float2* wrow = (const float2*)(sm + i*130);
        float tb = sth[64];
        float p0=0,p1=0,p2=0,p3=0,s0=0,s1=0,s2=0,s3=0;
        float a0=tb,a1=tb,a2=tb,a3=tb;       // theta: bias-first like before
        #pragma unroll 8
        for (int c = 0; c < 64; ++c) {
            float2 xa = *(const float2*)(xb + c*4096);
            float2 xc = *(const float2*)(xb + c*4096 + 64);
            float2 w  = wrow[c];             // {phi_w, psi_w}
            float st  = sth[c];              // broadcast read
            p0 += xa.x*w.x; p1 += xa.y*w.x; p2 += xc.x*w.x; p3 += xc.y*w.x;
            s0 += xa.x*w.y; s1 += xa.y*w.y; s2 += xc.x*w.y; s3 += xc.y*w.y;
            a0 += xa.x*st;  a1 += xa.y*st;  a2 += xc.x*st;  a3 += xc.y*st;
        }
        float pv = fmaxf(fmaxf(p0,p1), fmaxf(p2,p3)) + phi_b[i];
        float sv = fmaxf(fmaxf(s0,s1), fmaxf(s2,s3)) + psi_b[i];
        spsi[mIdx*33 + i] = sv;
        float v = pv * cp_w[32 + i];
        v += __shfl_xor(v, 16, 32);
        v += __shfl_xor(v,  8, 32);
        v += __shfl_xor(v,  4, 32);
        v += __shfl_xor(v,  2, 32);
        v += __shfl_xor(v,  1, 32);
        if (i == 0) {
            stg(&ws[OFF_BB + (b<<10) + m], v);
            int nb = (b<<12) + ph*128 + pw*2;   // pixel (2ph,2pw)
            stg(&ws[OFF_A + nb],      a0);
            stg(&ws[OFF_A + nb + 1],  a1);
            stg(&ws[OFF_A + nb + 64], a2);
            stg(&ws[OFF_A + nb + 65], a3);
        }
        __syncthreads();
        #pragma unroll
        for (int rep = 0; rep < 2; ++rep) {
            int idx = tid + (rep << 10);     // 2048 outputs = 32 m x 64 o
            int ml = idx >> 6, o = idx & 63;
            const float* pr = &spsi[ml*33];  // wave-uniform ml: broadcast
            const float* wr = &sWw[o*33];    // (o+i)%32: 2-way max (free)
            float u = 0;
            #pragma unroll
            for (int i2 = 0; i2 < 32; ++i2) u += pr[i2]*wr[i2];
            stg(&ws[OFF_U + (((b<<10) + (sub<<5) + ml) << 6) + o], u);
        }
    }
    // gen1 (per-batch), with one-time ready-flag check before first RMW
    __syncthreads();
    if (tid == 0) {
        while ((ldgu(&bars[288]) ^ ldgu(&bars[289])) != 0xFFFFFFFFu)
            __builtin_amdgcn_s_sleep(2);
        unsigned* ctr = bars + ((b + 1) << 5);
        __hip_atomic_fetch_add(ctr, 1u, __ATOMIC_RELAXED,
                               __HIP_MEMORY_SCOPE_AGENT);
        while (ldgu(ctr) < 32u) __builtin_amdgcn_s_sleep(2);
    }
    __syncthreads();

    // ---------- Phase 2: rank bb, k_n per pixel, per-b histogram ----------
    {
        float* sb = sh;
        sb[tid] = ldg1(&ws[OFF_BB + (b<<10) + tid]);
        __syncthreads();
        {   // rank 32 m's of this chunk (32 lanes per m, integer-exact)
            int ml = tid >> 5, jl = tid & 31;
            int m = (sub << 5) + ml;
            float vv = sb[m];
            int cnt = 0;
            for (int s = 0; s < 32; ++s) {
                int j = jl + (s << 5);
                float u = sb[j];
                cnt += (u > vv || (u == vv && j < m)) ? 1 : 0;
            }
            cnt += __shfl_xor(cnt,  1, 32);
            cnt += __shfl_xor(cnt,  2, 32);
            cnt += __shfl_xor(cnt,  4, 32);
            cnt += __shfl_xor(cnt,  8, 32);
            cnt += __shfl_xor(cnt, 16, 32);
            if (jl == 0) {
                stg(&ws[OFF_SBB + (b<<10) + cnt], vv);
                stgi(&((int*)ws)[OFF_PERM + (b<<10) + cnt], m);
            }
        }
        {   // k_n for 128 pixels (8 lanes per pixel) + hist atomics
            int l = tid >> 3, jl = tid & 7;
            int n = (sub << 7) + l;
            float av = ldg1(&ws[OFF_A + (b<<12) + n]);
            float tt = -av;
            const float2* sb2 = (const float2*)sb;
            int cnt = 0;
            for (int s = 0; s < 64; ++s) {
                float2 u = sb2[jl + (s << 3)];  // 8 distinct addrs: free
                cnt += (u.x > tt) ? 1 : 0;
                cnt += (u.y > tt) ? 1 : 0;
            }
            cnt += __shfl_xor(cnt, 1, 8);
            cnt += __shfl_xor(cnt, 2, 8);
            cnt += __shfl_xor(cnt, 4, 8);
            if (jl == 0) {
                stgi(&((int*)ws)[OFF_KK + (b<<12) + n], cnt);
                atomicAdd(&ws[OFF_HC + b*1025 + cnt], 1.0f);
                atomicAdd(&ws[OFF_HS + b*1025 + cnt], av);
                atomicAdd(&ws[OFF_HS2 + b*1025 + cnt], av*av);
            }
        }
    }
    gbarBatch(ws, b, 64u);   // gen2 (per-batch)

    // ---------- Phase 3: sorted prefixes T1/T2 + BN moment partials ------
    // ALL 256 blocks: (b, og=sub), 2 output channels per block.
    {
        int obase = sub << 1;
        float* ssort = sh;
        int*   sperm = (int*)(sh + 1024);
        float* shc   = sh + 2048;
        float* shs   = sh + 3076;
        float* shs2  = sh + 4104;
        float* swp1  = sh + 5132;   // 32: per-(wave, o2) partials
        float* swp2  = sh + 5164;
        ssort[tid] = ldg1(&ws[OFF_SBB + (b<<10) + tid]);
        sperm[tid] = ldgi(&((const int*)ws)[OFF_PERM + (b<<10) + tid]);
        shc[tid]  = ldg1(&ws[OFF_HC  + b*1025 + tid]);
        shs[tid]  = ldg1(&ws[OFF_HS  + b*1025 + tid]);
        shs2[tid] = ldg1(&ws[OFF_HS2 + b*1025 + tid]);
        if (tid == 0) {
            shc[1024]  = ldg1(&ws[OFF_HC  + b*1025 + 1024]);
            shs[1024]  = ldg1(&ws[OFF_HS  + b*1025 + 1024]);
            shs2[1024] = ldg1(&ws[OFF_HS2 + b*1025 + 1024]);
        }
        __syncthreads();
        int ch = tid >> 1, o2 = tid & 1;            // 512 chunks x 2 o
        int o  = obase + o2;
        int wv = tid >> 6, chl = (tid & 63) >> 1;   // 32 chunks per wave
        const float* Ub = ws + OFF_U + (b<<16) + o;
        float p[2], sp[2];
        float s1 = 0, s2 = 0;
        #pragma unroll
        for (int jl = 0; jl < 2; ++jl) {
            int jj = (ch<<1) + jl;
            float v = ldg1(&Ub[sperm[jj]<<6]);
            p[jl] = v;
            sp[jl] = ssort[jj]*v;
            s1 += v; s2 += sp[jl];
        }
        float own1 = s1, own2 = s2;
        #pragma unroll
        for (int d = 1; d < 32; d <<= 1) {
            float u1 = __shfl_up(s1, d<<1, 64);
            float u2 = __shfl_up(s2, d<<1, 64);
            if (chl >= d) { s1 += u1; s2 += u2; }
        }
        if (chl == 31) { swp1[(wv<<1)+o2] = s1; swp2[(wv<<1)+o2] = s2; }
        __syncthreads();
        float off1 = 0, off2 = 0;
        for (int w = 0; w < 16; ++w) {
            if (w < wv) { off1 += swp1[(w<<1)+o2]; off2 += swp2[(w<<1)+o2]; }
        }
        float run1 = off1 + s1 - own1;   // exclusive prefix before chunk ch
        float run2 = off2 + s2 - own2;
        float* T1 = ws + OFF_T1 + b*65600 + o;
        float* T2 = ws + OFF_T2 + b*65600 + o;
        if (ch == 0) { stg(&T1[0], 0.0f); stg(&T2[0], 0.0f); }  // k=0 row
        const float inv = 1.0f/1024.0f;
        float m1 = 0, m2 = 0;
        #pragma unroll
        for (int jl = 0; jl < 2; ++jl) {
            int k = (ch<<1) + jl + 1;
            run1 += p[jl]; run2 += sp[jl];
            float t1 = run1*inv, t2 = run2*inv;
            stg(&T1[k<<6], t1);
            stg(&T2[k<<6], t2);
            float c = shc[k], sa_ = shs[k], sa2 = shs2[k];
            m1 += sa_*t1 + c*t2;
            m2 += (sa2*t1 + 2.0f*sa_*t2)*t1 + c*t2*t2;
        }
        // reduce moments over chl (lane bits 1..5), keep o2 (bit 0)
        m1 += __shfl_xor(m1,  2, 64); m2 += __shfl_xor(m2,  2, 64);
        m1 += __shfl_xor(m1,  4, 64); m2 += __shfl_xor(m2,  4, 64);
        m1 += __shfl_xor(m1,  8, 64); m2 += __shfl_xor(m2,  8, 64);
        m1 += __shfl_xor(m1, 16, 64); m2 += __shfl_xor(m2, 16, 64);
        m1 += __shfl_xor(m1, 32, 64); m2 += __shfl_xor(m2, 32, 64);
        __syncthreads();   // swp reuse
        if (chl == 0) { swp1[(wv<<1)+o2] = m1; swp2[(wv<<1)+o2] = m2; }
        __syncthreads();
        if (tid < 2) {
            float a1 = 0, a2 = 0;
            for (int w = 0; w < 16; ++w) {
                a1 += swp1[(w<<1)+tid]; a2 += swp2[(w<<1)+tid];
            }
            stg(&ws[OFF_MP1 + (b<<6) + obase + tid], a1);
            stg(&ws[OFF_MP2 + (b<<6) + obase + tid], a2);
        }
    }
    // gen3: arrive per-batch, last of batch bumps global root; wait
    // per-batch NOW, defer the global root poll until after the gather.
    __syncthreads();
    if (tid == 0) {
        unsigned* ctr = bars + ((b + 1) << 5);
        unsigned old = __hip_atomic_fetch_add(ctr, 1u, __ATOMIC_RELAXED,
                                              __HIP_MEMORY_SCOPE_AGENT);
        if (old == 95u)
            __hip_atomic_fetch_add(&bars[0], 1u, __ATOMIC_RELAXED,
                                   __HIP_MEMORY_SCOPE_AGENT);
        while (ldgu(ctr) < 96u) __builtin_amdgcn_s_sleep(2);
    }
    __syncthreads();

    // ---------- Phase 4: output tile (128 pixels per block) --------------
    {
        float* tile = sh;               // 64 o x 129 (pad)
        float* sa = sh + 8256;          // a for 128 pixels
        int*   sk = (int*)(sh + 8384);  // k for 128 pixels
        float* sA = sh + 8512;
        float* sD = sh + 8576;
        int n0 = sub << 7;
        if (tid < 128) {
            sa[tid] = ldg1(&ws[OFF_A + (b<<12) + n0 + tid]);
            sk[tid] = ldgi(&((const int*)ws)[OFF_KK + (b<<12) + n0 + tid]);
        }
        __syncthreads();
        const float* T1 = ws + OFF_T1 + b*65600;
        const float* T2 = ws + OFF_T2 + b*65600;
        {   // raw gather: A/D applied later (overlaps global straggler wait)
            int o = tid & 63, ng = tid >> 6;   // 16 groups x 8 n
            #pragma unroll
            for (int j = 0; j < 8; ++j) {
                int n = (ng << 3) + j;
                int k = sk[n];                 // wave-uniform -> T coalesced
                float a = sa[n];
                tile[o*129 + n] = a*ldg1(&T1[(k<<6) + o])
                                  + ldg1(&T2[(k<<6) + o]);
            }
        }
        if (tid == 0) {   // global root: all batches' P3 done (moments)
            while (ldgu(&bars[0]) < 8u) __builtin_amdgcn_s_sleep(2);
        }
        __syncthreads();
        if (tid < 64) {
            const float Ninv = 1.0f/32768.0f;
            float m1s = 0, m2s = 0;
            #pragma unroll
            for (int b3 = 0; b3 < 8; ++b3) {
                m1s += ldg1(&ws[OFF_MP1 + (b3<<6) + tid]);
                m2s += ldg1(&ws[OFF_MP2 + (b3<<6) + tid]);
            }
            float m1 = m1s * Ninv;
            float m2 = m2s * Ninv;
            float wb = Wb[tid];
            float mu  = m1 + wb;
            float E2  = m2 + 2.0f*wb*m1 + wb*wb;
            float var = E2 - mu*mu;
            float A = gamma[tid] * rsqrtf(var + 1e-5f);
            sA[tid] = A;
            sD[tid] = beta[tid] + A*(wb - mu);
        }
        __syncthreads();
        {
            int n = tid & 127, og2 = tid >> 7;  // 8 groups x 8 o
            #pragma unroll
            for (int j = 0; j < 8; ++j) {
                int o = (og2 << 3) + j;
                int idx = ((b<<6) + o)*4096 + n0 + n;
                out[idx] = sA[o]*tile[o*129 + n] + sD[o] + x[idx];
            }
        }
    }
}

extern "C" void kernel_launch(void* const* d_in, const int* in_sizes, int n_in,
                              void* d_out, int out_size, void* d_ws, size_t ws_size,
                              hipStream_t stream)
{
    const float* x       = (const float*)d_in[0];
    const float* theta_w = (const float*)d_in[1];
    const float* theta_b = (const float*)d_in[2];
    const float* phi_w   = (const float*)d_in[3];
    const float* phi_b   = (const float*)d_in[4];
    const float* psi_w   = (const float*)d_in[5];
    const float* psi_b   = (const float*)d_in[6];
    const float* cp_w    = (const float*)d_in[7];
    const float* Ww      = (const float*)d_in[8];
    const float* Wb      = (const float*)d_in[9];
    const float* gamma   = (const float*)d_in[10];
    const float* beta    = (const float*)d_in[11];
    float* ws  = (float*)d_ws;
    float* out = (float*)d_out;

    kMega<<<256, 1024, 0, stream>>>(x, theta_w, theta_b, phi_w, phi_b,
                                    psi_w, psi_b, cp_w, Ww, Wb,
                                    gamma, beta, ws, out);
}

// Round 7
// 126.224 us; speedup vs baseline: 1.0912x; 1.0484x over previous
//
#include <hip/hip_runtime.h>

// B=8, C=64, H=W=64, CI=32, N=4096 pixels, M=1024 pooled.
// y[b,n,:] = (a_n*S1[k_n,:] + S2[k_n,:])/1024 ; only W_w . y is needed, so
// track U = Ww.psi (64-dim) and its sorted-order prefixes T1/T2 directly.
// BN stats from per-k scalars (cnt, sum a, sum a^2) x T rows - no Gram.
//
// r12: (1) SPLIT at the only global sync: kA = P1->gen1->P2->gen2->P3
// (per-batch barriers only), kB = P4. r0 accounting showed graph kernel
// boundaries cost ~1us -- vs the ~10-25us any in-kernel global rendezvous
// has cost in r6-r11. kB uses PLAIN cached loads (post-boundary coherent):
// T reads get L2 reuse. (2) U stored TRANSPOSED U_T[b][o][m]: P1's U-loop
// is re-indexed o-major (coalesced 128B stores), and P3 reads its two U
// rows as contiguous 4KB (was a 32-way-scattered sc1 gather -- the r6
// FETCH inflation) then scatters into sorted order in LDS via rank[m]
// (P2 stores RK = rank; SBB/PERM dropped). P3 numerics value-identical.
#define OFF_A    0         // a[b][n]               : 32768 floats
#define OFF_BB   32768     // bb[b][m]              : 8192
#define OFF_RK   40960     // rank[b][m] (int)      : 8192
#define OFF_U    57344     // U_T[b][o][m]          : 8*64*1024 = 524288
#define OFF_T1   581632    // T1[b][k<=1024][o]     : 8*1025*64 = 524800
#define OFF_T2   1106432   // T2[b][k][o]           : 524800
#define OFF_KK   1631232   // k[b][n] (int)         : 32768
#define OFF_MP1  1664000   // moment1 partials [b][o] : 512
#define OFF_MP2  1664512   // moment2 partials [b][o] : 512
#define OFF_HC   1665024   // hist cnt[b][1025]     : 8200
#define OFF_HS   1673224   // hist sum_a[b][1025]   : 8200
#define OFF_HS2  1681424   // hist sum_a2[b][1025]  : 8200
#define OFF_BAR  1689624   // u32: batch b ctr @32*(b+1); flags @288,289

// Coherent (sc1, L2-bypass) scalar access helpers for cross-block data
// inside kA (per-XCD L2s are not coherent across blocks).
__device__ __forceinline__ void stg(float* p, float v) {
    __hip_atomic_store(p, v, __ATOMIC_RELAXED, __HIP_MEMORY_SCOPE_AGENT);
}
__device__ __forceinline__ float ldg1(const float* p) {
    return __hip_atomic_load(p, __ATOMIC_RELAXED, __HIP_MEMORY_SCOPE_AGENT);
}
__device__ __forceinline__ void stgi(int* p, int v) {
    __hip_atomic_store(p, v, __ATOMIC_RELAXED, __HIP_MEMORY_SCOPE_AGENT);
}
__device__ __forceinline__ int ldgi(const int* p) {
    return __hip_atomic_load(p, __ATOMIC_RELAXED, __HIP_MEMORY_SCOPE_AGENT);
}
__device__ __forceinline__ void stgu(unsigned* p, unsigned v) {
    __hip_atomic_store(p, v, __ATOMIC_RELAXED, __HIP_MEMORY_SCOPE_AGENT);
}
__device__ __forceinline__ unsigned ldgu(const unsigned* p) {
    return __hip_atomic_load(p, __ATOMIC_RELAXED, __HIP_MEMORY_SCOPE_AGENT);
}

// Per-batch barrier: 32 blocks of batch b arrive on ctr[b] (relaxed RMW,
// one line per batch, 8 lines in parallel device-wide), poll own counter.
// Release = vmcnt drain at the preceding __syncthreads (r4/r6-validated).
__device__ __forceinline__ void gbarBatch(float* ws, int b, unsigned goal)
{
    __syncthreads();
    if (threadIdx.x == 0) {
        unsigned* ctr = (unsigned*)(ws + OFF_BAR) + ((b + 1) << 5);
        __hip_atomic_fetch_add(ctr, 1u, __ATOMIC_RELAXED,
                               __HIP_MEMORY_SCOPE_AGENT);
        while (ldgu(ctr) < goal) __builtin_amdgcn_s_sleep(2);
    }
    __syncthreads();
}

// LDS carve for kA (floats), phases reuse one 7396-float block (29.6 KB):
// P1: sm[0..4160) sth[4160..4228) spsi[4228..5284) sWw[5284..7396)
// P2: sb[0..1024)
// P3: ssb[0..1024) sU0[1024..2048) sU1[2048..3072) shc[3072..4097)
//     shs[4097..5122) shs2[5122..6147) swp1[6148..6180) swp2[6180..6212)
__global__ __launch_bounds__(1024) void kA(
    const float* __restrict__ x, const float* __restrict__ theta_w,
    const float* __restrict__ theta_b, const float* __restrict__ phi_w,
    const float* __restrict__ phi_b, const float* __restrict__ psi_w,
    const float* __restrict__ psi_b, const float* __restrict__ cp_w,
    const float* __restrict__ Ww, float* __restrict__ ws)
{
    __shared__ float sh[7396];
    const int tid = threadIdx.x;
    const int bid = blockIdx.x;
    const int b   = bid >> 5;     // 32 blocks per batch image
    const int sub = bid & 31;
    unsigned* bars = (unsigned*)(ws + OFF_BAR);

    // ---------- Phase 1: phi/psi conv+pool -> bb, U_T ; theta -> a --------
    {
        if (bid == 0 && tid == 0) {     // zero 8 batch counters
            for (int i = 0; i < 8; ++i) stgu(&bars[(i + 1) << 5], 0u);
        }
        // zero this block's slice of ITS OWN batch's hist (3075 floats
        // over 32 blocks); visible to batch peers at gen1 -- used in P2.
        if (tid < 97) {
            int e = sub*97 + tid;
            if (e < 1025)      stg(&ws[OFF_HC  + b*1025 + e], 0.0f);
            else if (e < 2050) stg(&ws[OFF_HS  + b*1025 + e - 1025], 0.0f);
            else if (e < 3075) stg(&ws[OFF_HS2 + b*1025 + e - 2050], 0.0f);
        }
        float* sm   = sh;          // 32 i-rows x 130: interleaved {phi,psi}
        float* sth  = sh + 4160;   // tw_eff[64] + tb_eff
        float* spsi = sh + 4228;   // 32 m-rows x 32 i (pad 33)
        float* sWw  = sh + 5284;   // 64 o-rows x 32 i (pad 33)
        for (int e = tid; e < 2048; e += 1024) {
            int i = e >> 6, c = e & 63;
            sm[i*130 + 2*c]     = phi_w[e];
            sm[i*130 + 2*c + 1] = psi_w[e];
        }
        for (int e = tid; e < 2048; e += 1024)
            sWw[(e >> 5)*33 + (e & 31)] = Ww[(e >> 5)*33 + (e & 31)];
        if (tid < 64) {
            float s = 0;
            for (int i = 0; i < 32; ++i) s += cp_w[i]*theta_w[i*64 + tid];
            sth[tid] = s;
        } else if (tid == 64) {
            float s = 0;
            for (int i = 0; i < 32; ++i) s += cp_w[i]*theta_b[i];
            sth[64] = s;
        }
        __syncthreads();   // drains vmcnt -> block0's counter zeros visible
        if (bid == 0 && tid == 0) {    // publish ready flags (poison-proof)
            stgu(&bars[288], 0x5A5A5A5Au);
            stgu(&bars[289], 0xA5A5A5A5u);
        }
        int i = tid & 31;
        int mIdx = tid >> 5;                 // 0..31
        int m = (sub << 5) + mIdx;
        int ph = m >> 5, pw = m & 31;
        const float* xb = x + b*262144 + ph*128 + pw*2;
        const float2* wrow = (const float2*)(sm + i*130);
        float tb = sth[64];
        float p0=0,p1=0,p2=0,p3=0,s0=0,s1=0,s2=0,s3=0;
        float a0=tb,a1=tb,a2=tb,a3=tb;       // theta: bias-first like before
        #pragma unroll 8
        for (int c = 0; c < 64; ++c) {
            float2 xa = *(const float2*)(xb + c*4096);
            float2 xc = *(const float2*)(xb + c*4096 + 64);
            float2 w  = wrow[c];             // {phi_w, psi_w}
            float st  = sth[c];              // broadcast read
            p0 += xa.x*w.x; p1 += xa.y*w.x; p2 += xc.x*w.x; p3 += xc.y*w.x;
            s0 += xa.x*w.y; s1 += xa.y*w.y; s2 += xc.x*w.y; s3 += xc.y*w.y;
            a0 += xa.x*st;  a1 += xa.y*st;  a2 += xc.x*st;  a3 += xc.y*st;
        }
        float pv = fmaxf(fmaxf(p0,p1), fmaxf(p2,p3)) + phi_b[i];
        float sv = fmaxf(fmaxf(s0,s1), fmaxf(s2,s3)) + psi_b[i];
        spsi[mIdx*33 + i] = sv;
        float v = pv * cp_w[32 + i];
        v += __shfl_xor(v, 16, 32);
        v += __shfl_xor(v,  8, 32);
        v += __shfl_xor(v,  4, 32);
        v += __shfl_xor(v,  2, 32);
        v += __shfl_xor(v,  1, 32);
        if (i == 0) {
            stg(&ws[OFF_BB + (b<<10) + m], v);
            int nb = (b<<12) + ph*128 + pw*2;   // pixel (2ph,2pw)
            stg(&ws[OFF_A + nb],      a0);
            stg(&ws[OFF_A + nb + 1],  a1);
            stg(&ws[OFF_A + nb + 64], a2);
            stg(&ws[OFF_A + nb + 65], a3);
        }
        __syncthreads();
        // U-loop, o-major: lane ml = m-low, 32 lanes store 128B contiguous
        #pragma unroll
        for (int rep = 0; rep < 2; ++rep) {
            int o  = (tid >> 5) + (rep << 5);   // 0..63
            int ml = tid & 31;
            const float* pr = &spsi[ml*33];     // 32 banks, 2-way: free
            const float* wr = &sWw[o*33];       // wave-uniform-ish: bcast
            float u = 0;
            #pragma unroll
            for (int i2 = 0; i2 < 32; ++i2) u += pr[i2]*wr[i2];
            stg(&ws[OFF_U + (((b<<6) + o)<<10) + (sub<<5) + ml], u);
        }
    }
    // gen1 (per-batch), with one-time ready-flag check before first RMW
    __syncthreads();
    if (tid == 0) {
        while ((ldgu(&bars[288]) ^ ldgu(&bars[289])) != 0xFFFFFFFFu)
            __builtin_amdgcn_s_sleep(2);
        unsigned* ctr = bars + ((b + 1) << 5);
        __hip_atomic_fetch_add(ctr, 1u, __ATOMIC_RELAXED,
                               __HIP_MEMORY_SCOPE_AGENT);
        while (ldgu(ctr) < 32u) __builtin_amdgcn_s_sleep(2);
    }
    __syncthreads();

    // ---------- Phase 2: rank bb -> RK, k_n per pixel, per-b histogram ----
    {
        float* sb = sh;
        sb[tid] = ldg1(&ws[OFF_BB + (b<<10) + tid]);
        __syncthreads();
        {   // rank 32 m's of this chunk (32 lanes per m, integer-exact)
            int ml = tid >> 5, jl = tid & 31;
            int m = (sub << 5) + ml;
            float vv = sb[m];
            int cnt = 0;
            for (int s = 0; s < 32; ++s) {
                int j = jl + (s << 5);
                float u = sb[j];
                cnt += (u > vv || (u == vv && j < m)) ? 1 : 0;
            }
            cnt += __shfl_xor(cnt,  1, 32);
            cnt += __shfl_xor(cnt,  2, 32);
            cnt += __shfl_xor(cnt,  4, 32);
            cnt += __shfl_xor(cnt,  8, 32);
            cnt += __shfl_xor(cnt, 16, 32);
            if (jl == 0)
                stgi(&((int*)ws)[OFF_RK + (b<<10) + m], cnt);
        }
        {   // k_n for 128 pixels (8 lanes per pixel) + hist atomics
            int l = tid >> 3, jl = tid & 7;
            int n = (sub << 7) + l;
            float av = ldg1(&ws[OFF_A + (b<<12) + n]);
            float tt = -av;
            const float2* sb2 = (const float2*)sb;
            int cnt = 0;
            for (int s = 0; s < 64; ++s) {
                float2 u = sb2[jl + (s << 3)];  // 8 distinct addrs: free
                cnt += (u.x > tt) ? 1 : 0;
                cnt += (u.y > tt) ? 1 : 0;
            }
            cnt += __shfl_xor(cnt, 1, 8);
            cnt += __shfl_xor(cnt, 2, 8);
            cnt += __shfl_xor(cnt, 4, 8);
            if (jl == 0) {
                stgi(&((int*)ws)[OFF_KK + (b<<12) + n], cnt);
                atomicAdd(&ws[OFF_HC + b*1025 + cnt], 1.0f);
                atomicAdd(&ws[OFF_HS + b*1025 + cnt], av);
                atomicAdd(&ws[OFF_HS2 + b*1025 + cnt], av*av);
            }
        }
    }
    gbarBatch(ws, b, 64u);   // gen2 (per-batch)

    // ---------- Phase 3: sorted prefixes T1/T2 + BN moment partials ------
    // All 256 blocks: (b, og=sub), 2 output channels per block. U/BB/RK
    // loads fully coalesced; sorted order built by LDS scatter via rank.
    {
        int obase = sub << 1;
        float* ssb  = sh;           // sorted bb
        float* sU0  = sh + 1024;    // sorted U, o2=0
        float* sU1  = sh + 2048;    // sorted U, o2=1
        float* shc  = sh + 3072;
        float* shs  = sh + 4097;
        float* shs2 = sh + 5122;
        float* swp1 = sh + 6148;    // 32: per-(wave, o2) partials
        float* swp2 = sh + 6180;
        {
            float bbv = ldg1(&ws[OFF_BB + (b<<10) + tid]);
            int   rk  = ldgi(&((const int*)ws)[OFF_RK + (b<<10) + tid]);
            float u0  = ldg1(&ws[OFF_U + (((b<<6) + obase)<<10) + tid]);
            float u1  = ldg1(&ws[OFF_U + (((b<<6) + obase + 1)<<10) + tid]);
            ssb[rk] = bbv;
            sU0[rk] = u0;
            sU1[rk] = u1;
            shc[tid]  = ldg1(&ws[OFF_HC  + b*1025 + tid]);
            shs[tid]  = ldg1(&ws[OFF_HS  + b*1025 + tid]);
            shs2[tid] = ldg1(&ws[OFF_HS2 + b*1025 + tid]);
            if (tid == 0) {
                shc[1024]  = ldg1(&ws[OFF_HC  + b*1025 + 1024]);
                shs[1024]  = ldg1(&ws[OFF_HS  + b*1025 + 1024]);
                shs2[1024] = ldg1(&ws[OFF_HS2 + b*1025 + 1024]);
            }
        }
        __syncthreads();
        int ch = tid >> 1, o2 = tid & 1;            // 512 chunks x 2 o
        int o  = obase + o2;
        int wv = tid >> 6, chl = (tid & 63) >> 1;   // 32 chunks per wave
        const float* sU = sh + 1024 + (o2 << 10);
        float p[2], sp[2];
        float s1 = 0, s2 = 0;
        #pragma unroll
        for (int jl = 0; jl < 2; ++jl) {
            int jj = (ch<<1) + jl;
            float v = sU[jj];
            p[jl] = v;
            sp[jl] = ssb[jj]*v;
            s1 += v; s2 += sp[jl];
        }
        float own1 = s1, own2 = s2;
        #pragma unroll
        for (int d = 1; d < 32; d <<= 1) {
            float u1 = __shfl_up(s1, d<<1, 64);
            float u2 = __shfl_up(s2, d<<1, 64);
            if (chl >= d) { s1 += u1; s2 += u2; }
        }
        if (chl == 31) { swp1[(wv<<1)+o2] = s1; swp2[(wv<<1)+o2] = s2; }
        __syncthreads();
        float off1 = 0, off2 = 0;
        for (int w = 0; w < 16; ++w) {
            if (w < wv) { off1 += swp1[(w<<1)+o2]; off2 += swp2[(w<<1)+o2]; }
        }
        float run1 = off1 + s1 - own1;   // exclusive prefix before chunk ch
        float run2 = off2 + s2 - own2;
        float* T1 = ws + OFF_T1 + b*65600 + o;
        float* T2 = ws + OFF_T2 + b*65600 + o;
        if (ch == 0) { stg(&T1[0], 0.0f); stg(&T2[0], 0.0f); }  // k=0 row
        const float inv = 1.0f/1024.0f;
        float m1 = 0, m2 = 0;
        #pragma unroll
        for (int jl = 0; jl < 2; ++jl) {
            int k = (ch<<1) + jl + 1;
            run1 += p[jl]; run2 += sp[jl];
            float t1 = run1*inv, t2 = run2*inv;
            stg(&T1[k<<6], t1);
            stg(&T2[k<<6], t2);
            float c = shc[k], sa_ = shs[k], sa2 = shs2[k];
            m1 += sa_*t1 + c*t2;
            m2 += (sa2*t1 + 2.0f*sa_*t2)*t1 + c*t2*t2;
        }
        // reduce moments over chl (lane bits 1..5), keep o2 (bit 0)
        m1 += __shfl_xor(m1,  2, 64); m2 += __shfl_xor(m2,  2, 64);
        m1 += __shfl_xor(m1,  4, 64); m2 += __shfl_xor(m2,  4, 64);
        m1 += __shfl_xor(m1,  8, 64); m2 += __shfl_xor(m2,  8, 64);
        m1 += __shfl_xor(m1, 16, 64); m2 += __shfl_xor(m2, 16, 64);
        m1 += __shfl_xor(m1, 32, 64); m2 += __shfl_xor(m2, 32, 64);
        __syncthreads();   // swp reuse
        if (chl == 0) { swp1[(wv<<1)+o2] = m1; swp2[(wv<<1)+o2] = m2; }
        __syncthreads();
        if (tid < 2) {
            float a1 = 0, a2 = 0;
            for (int w = 0; w < 16; ++w) {
                a1 += swp1[(w<<1)+tid]; a2 += swp2[(w<<1)+tid];
            }
            stg(&ws[OFF_MP1 + (b<<6) + obase + tid], a1);
            stg(&ws[OFF_MP2 + (b<<6) + obase + tid], a2);
        }
    }
    // kernel ends: stream order is the global barrier before kB.
}

// kB (= P4): plain cached loads everywhere -- the kernel boundary gives
// device-wide visibility of kA's MALL-resident sc1 data, and L2 now
// caches the T rows (reused ~4x within a batch).
__global__ __launch_bounds__(1024) void kB(
    const float* __restrict__ x, const float* __restrict__ Wb,
    const float* __restrict__ gamma, const float* __restrict__ beta,
    const float* __restrict__ ws, float* __restrict__ out)
{
    __shared__ float tile[64*129];
    __shared__ float sa[128];
    __shared__ int   sk[128];
    __shared__ float sA[64];
    __shared__ float sD[64];
    const int tid = threadIdx.x;
    const int b   = blockIdx.x >> 5;
    const int n0  = (blockIdx.x & 31) << 7;
    if (tid < 128) {
        sa[tid] = ws[OFF_A + (b<<12) + n0 + tid];
        sk[tid] = ((const int*)ws)[OFF_KK + (b<<12) + n0 + tid];
    }
    if (tid < 64) {
        const float Ninv = 1.0f/32768.0f;
        float m1s = 0, m2s = 0;
        #pragma unroll
        for (int b3 = 0; b3 < 8; ++b3) {
            m1s += ws[OFF_MP1 + (b3<<6) + tid];
            m2s += ws[OFF_MP2 + (b3<<6) + tid];
        }
        float m1 = m1s * Ninv;
        float m2 = m2s * Ninv;
        float wb = Wb[tid];
        float mu  = m1 + wb;
        float E2  = m2 + 2.0f*wb*m1 + wb*wb;
        float var = E2 - mu*mu;
        float A = gamma[tid] * rsqrtf(var + 1e-5f);
        sA[tid] = A;
        sD[tid] = beta[tid] + A*(wb - mu);
    }
    __syncthreads();
    const float* T1 = ws + OFF_T1 + b*65600;
    const float* T2 = ws + OFF_T2 + b*65600;
    {
        int o = tid & 63, ng = tid >> 6;   // 16 waves x 8 n each
        float Ao = sA[o], Do = sD[o];
        #pragma unroll
        for (int j = 0; j < 8; ++j) {
            int n = (ng << 3) + j;
            int k = sk[n];                 // wave-uniform -> T coalesced
            float a = sa[n];
            float t1 = T1[(k<<6) + o];
            float t2 = T2[(k<<6) + o];
            tile[o*129 + n] = Ao*(a*t1 + t2) + Do;
        }
    }
    __syncthreads();
    {
        int n = tid & 127, og = tid >> 7;  // 8 groups x 8 o
        #pragma unroll
        for (int j = 0; j < 8; ++j) {
            int o = (og << 3) + j;
            int idx = ((b<<6) + o)*4096 + n0 + n;
            out[idx] = tile[o*129 + n] + x[idx];
        }
    }
}

extern "C" void kernel_launch(void* const* d_in, const int* in_sizes, int n_in,
                              void* d_out, int out_size, void* d_ws, size_t ws_size,
                              hipStream_t stream)
{
    const float* x       = (const float*)d_in[0];
    const float* theta_w = (const float*)d_in[1];
    const float* theta_b = (const float*)d_in[2];
    const float* phi_w   = (const float*)d_in[3];
    const float* phi_b   = (const float*)d_in[4];
    const float* psi_w   = (const float*)d_in[5];
    const float* psi_b   = (const float*)d_in[6];
    const float* cp_w    = (const float*)d_in[7];
    const float* Ww      = (const float*)d_in[8];
    const float* Wb      = (const float*)d_in[9];
    const float* gamma   = (const float*)d_in[10];
    const float* beta    = (const float*)d_in[11];
    float* ws  = (float*)d_ws;
    float* out = (float*)d_out;

    kA<<<256, 1024, 0, stream>>>(x, theta_w, theta_b, phi_w, phi_b,
                                 psi_w, psi_b, cp_w, Ww, ws);
    kB<<<256, 1024, 0, stream>>>(x, Wb, gamma, beta, ws, out);
}